// Round 1
// baseline (7354.544 us; speedup 1.0000x reference)
//
#include <hip/hip_runtime.h>
#include <hip/hip_bf16.h>
#include <math.h>

// Problem constants
#define B_  2
#define L_  2048
#define D_  1024
#define E_  2048
#define NN  16
#define RR  64
#define M_  4096   // B*L

// ---------------- embed gather ----------------
__global__ __launch_bounds__(256) void embed_kernel(const int* __restrict__ tokens,
    const float* __restrict__ embed, float* __restrict__ x) {
  int m = blockIdx.x;
  int tok = tokens[m];
  reinterpret_cast<float4*>(x + (size_t)m * D_)[threadIdx.x] =
      reinterpret_cast<const float4*>(embed + (size_t)tok * D_)[threadIdx.x];
}

// ---------------- rmsnorm (one block per row, D=1024) ----------------
__global__ __launch_bounds__(256) void rmsnorm_kernel(const float* __restrict__ x,
    const float* __restrict__ w, float* __restrict__ out) {
  __shared__ float red[4];
  int m = blockIdx.x, tid = threadIdx.x;
  float4 v = reinterpret_cast<const float4*>(x + (size_t)m * D_)[tid];
  float ss = v.x * v.x + v.y * v.y + v.z * v.z + v.w * v.w;
#pragma unroll
  for (int o = 32; o > 0; o >>= 1) ss += __shfl_down(ss, o);
  if ((tid & 63) == 0) red[tid >> 6] = ss;
  __syncthreads();
  float total = red[0] + red[1] + red[2] + red[3];
  float scale = rsqrtf(total * (1.0f / (float)D_) + 1e-5f);
  float4 wv = reinterpret_cast<const float4*>(w)[tid];
  float4 o4;
  o4.x = v.x * wv.x * scale;
  o4.y = v.y * wv.y * scale;
  o4.z = v.z * wv.z * scale;
  o4.w = v.w * wv.w * scale;
  reinterpret_cast<float4*>(out + (size_t)m * D_)[tid] = o4;
}

// ---------------- generic tiled f32 GEMM ----------------
// C[M,N] = A[M,K] * B[K,N]   (BT=false, B row-major K x N)
// C[M,N] = A[M,K] * B[N,K]^T (BT=true,  B row-major N x K)
// op: 0 = none, 1 = softplus(C + bias[col]), 2 = C += acc (residual)
__device__ __forceinline__ float softplusf(float v) {
  return (v > 20.f) ? v : log1pf(__expf(v));
}

template <bool BT>
__global__ __launch_bounds__(256) void gemm_f32(
    const float* __restrict__ A, const float* __restrict__ B, float* __restrict__ C,
    int M, int N, int K, int lda, int ldb, int ldc,
    int op, const float* __restrict__ bias) {
  __shared__ __align__(16) float As[16][64];
  __shared__ __align__(16) float Bs[16][64];
  const int tid = threadIdx.x;
  const int tx = tid & 15, ty = tid >> 4;
  const int bm = blockIdx.y << 6, bn = blockIdx.x << 6;
  float acc[4][4] = {};
  for (int k0 = 0; k0 < K; k0 += 16) {
    {  // A tile: As[k][m], coalesced float4 along K
      int r = tid >> 2, c = (tid & 3) << 2;
      const float* ap = A + (size_t)(bm + r) * lda + (k0 + c);
      float4 v = *reinterpret_cast<const float4*>(ap);
      As[c + 0][r] = v.x; As[c + 1][r] = v.y; As[c + 2][r] = v.z; As[c + 3][r] = v.w;
    }
    if (!BT) {  // B tile from K x N
      int r = tid >> 4, c = (tid & 15) << 2;
      float4 v;
      if (bn + c + 3 < N) {
        v = *reinterpret_cast<const float4*>(B + (size_t)(k0 + r) * ldb + (bn + c));
      } else {
        const float* bp = B + (size_t)(k0 + r) * ldb;
        v.x = (bn + c + 0 < N) ? bp[bn + c + 0] : 0.f;
        v.y = (bn + c + 1 < N) ? bp[bn + c + 1] : 0.f;
        v.z = (bn + c + 2 < N) ? bp[bn + c + 2] : 0.f;
        v.w = (bn + c + 3 < N) ? bp[bn + c + 3] : 0.f;
      }
      Bs[r][c + 0] = v.x; Bs[r][c + 1] = v.y; Bs[r][c + 2] = v.z; Bs[r][c + 3] = v.w;
    } else {  // B tile from N x K (transposed use)
      int r = tid >> 2, c = (tid & 3) << 2;
      const float* bp = B + (size_t)(bn + r) * ldb + (k0 + c);
      float4 v = *reinterpret_cast<const float4*>(bp);
      Bs[c + 0][r] = v.x; Bs[c + 1][r] = v.y; Bs[c + 2][r] = v.z; Bs[c + 3][r] = v.w;
    }
    __syncthreads();
#pragma unroll
    for (int k = 0; k < 16; ++k) {
      float4 a4 = *reinterpret_cast<const float4*>(&As[k][ty << 2]);
      float4 b4 = *reinterpret_cast<const float4*>(&Bs[k][tx << 2]);
      float a[4] = {a4.x, a4.y, a4.z, a4.w};
      float b[4] = {b4.x, b4.y, b4.z, b4.w};
#pragma unroll
      for (int i = 0; i < 4; ++i)
#pragma unroll
        for (int j = 0; j < 4; ++j) acc[i][j] = fmaf(a[i], b[j], acc[i][j]);
    }
    __syncthreads();
  }
#pragma unroll
  for (int i = 0; i < 4; ++i) {
    int row = bm + (ty << 2) + i;
#pragma unroll
    for (int j = 0; j < 4; ++j) {
      int col = bn + (tx << 2) + j;
      if (col < N) {
        float v = acc[i][j];
        if (op == 1) v = softplusf(v + bias[col]);
        else if (op == 2) v += C[(size_t)row * ldc + col];
        C[(size_t)row * ldc + col] = v;
      }
    }
  }
}

// ---------------- causal depthwise conv (K=4) + silu ----------------
// reads x-half of xz (cols [0,E)), writes xc
__global__ __launch_bounds__(256) void conv_silu_kernel(const float* __restrict__ xz,
    const float* __restrict__ cw, const float* __restrict__ cb, float* __restrict__ xc) {
  int idx = blockIdx.x * 256 + threadIdx.x;  // over B*L*E
  int e = idx & (E_ - 1);
  int t = (idx >> 11) & (L_ - 1);
  const float4 w4 = *reinterpret_cast<const float4*>(cw + e * 4);  // k = 0..3
  float s = cb[e];
  const float* base = xz + (size_t)(idx >> 11) * (2 * E_) + e;  // row (b*L + t)
  s = fmaf(w4.w, base[0], s);
  if (t >= 1) s = fmaf(w4.z, base[-(2 * E_)], s);
  if (t >= 2) s = fmaf(w4.y, base[-(4 * E_)], s);
  if (t >= 3) s = fmaf(w4.x, base[-(6 * E_)], s);
  xc[idx] = s / (1.f + __expf(-s));  // silu
}

// ---------------- selective scan + D-skip + silu(z) gating ----------------
// one block = 16 (b,e) pairs x N=16 states; LDS-staged 64-step chunks
__global__ __launch_bounds__(256) void scan_kernel(
    const float* __restrict__ dtp, const float* __restrict__ dblp,
    const float* __restrict__ xcp, const float* __restrict__ xzp,
    const float* __restrict__ Alogp, const float* __restrict__ Dp,
    float* __restrict__ yp) {
  __shared__ float s_dt[64][17], s_x[64][17], s_B[64][17], s_C[64][17], s_z[64][17];
  const int tid = threadIdx.x;
  const int p = tid >> 4, n = tid & 15;
  const int e0 = (blockIdx.x << 4) & (E_ - 1);
  const int b = blockIdx.x >> 7;  // 128 blocks per batch (E/16)
  const int e = e0 + p;
  const size_t bL = (size_t)b * L_;
  const float Av = -__expf(Alogp[e * NN + n]);
  const float Dv = Dp[e];
  float h = 0.f;
  const int lt = tid >> 2, lc = (tid & 3) << 2;  // loader coords
  for (int t0 = 0; t0 < L_; t0 += 64) {
    __syncthreads();
    {
      const size_t row = bL + t0 + lt;
      float4 v;
      v = *reinterpret_cast<const float4*>(dtp + row * E_ + e0 + lc);
      s_dt[lt][lc] = v.x; s_dt[lt][lc + 1] = v.y; s_dt[lt][lc + 2] = v.z; s_dt[lt][lc + 3] = v.w;
      v = *reinterpret_cast<const float4*>(xcp + row * E_ + e0 + lc);
      s_x[lt][lc] = v.x; s_x[lt][lc + 1] = v.y; s_x[lt][lc + 2] = v.z; s_x[lt][lc + 3] = v.w;
      v = *reinterpret_cast<const float4*>(xzp + row * (2 * E_) + E_ + e0 + lc);
      s_z[lt][lc] = v.x; s_z[lt][lc + 1] = v.y; s_z[lt][lc + 2] = v.z; s_z[lt][lc + 3] = v.w;
      v = *reinterpret_cast<const float4*>(dblp + row * 96 + RR + lc);
      s_B[lt][lc] = v.x; s_B[lt][lc + 1] = v.y; s_B[lt][lc + 2] = v.z; s_B[lt][lc + 3] = v.w;
      v = *reinterpret_cast<const float4*>(dblp + row * 96 + RR + NN + lc);
      s_C[lt][lc] = v.x; s_C[lt][lc + 1] = v.y; s_C[lt][lc + 2] = v.z; s_C[lt][lc + 3] = v.w;
    }
    __syncthreads();
    for (int tt = 0; tt < 64; ++tt) {
      float dtv = s_dt[tt][p];
      float xv = s_x[tt][p];
      float dA = __expf(dtv * Av);
      h = fmaf(h, dA, dtv * xv * s_B[tt][n]);
      float c = h * s_C[tt][n];
      c += __shfl_xor(c, 1);
      c += __shfl_xor(c, 2);
      c += __shfl_xor(c, 4);
      c += __shfl_xor(c, 8);
      if (n == 0) {
        float zv = s_z[tt][p];
        float sil = zv / (1.f + __expf(-zv));
        yp[(bL + t0 + tt) * E_ + e] = (c + xv * Dv) * sil;
      }
    }
  }
}

// ---------------- host ----------------
extern "C" void kernel_launch(void* const* d_in, const int* in_sizes, int n_in,
                              void* d_out, int out_size, void* d_ws, size_t ws_size,
                              hipStream_t stream) {
  const int*   tokens  = (const int*)d_in[0];
  const float* embed   = (const float*)d_in[1];
  const float* norm_w  = (const float*)d_in[2];
  const float* W_in    = (const float*)d_in[3];
  const float* conv_w  = (const float*)d_in[4];
  const float* conv_b  = (const float*)d_in[5];
  const float* W_xproj = (const float*)d_in[6];
  const float* W_dt    = (const float*)d_in[7];
  const float* dt_bias = (const float*)d_in[8];
  const float* A_log   = (const float*)d_in[9];
  const float* D_skip  = (const float*)d_in[10];
  const float* W_out   = (const float*)d_in[11];
  const float* fnw     = (const float*)d_in[12];
  const float* lm_head = (const float*)d_in[13];
  float* out = (float*)d_out;

  // small persistent scratch in ws (~35 MB)
  float* ws  = (float*)d_ws;
  float* x   = ws;             // 4,194,304 f32
  float* xn  = x + 4194304;    // 4,194,304
  float* dbl = xn + 4194304;   //   393,216

  // big transient scratch inside d_out (131M f32 available; all use finishes
  // before the final lm_head GEMM overwrites the full output)
  float* xz  = out;              // 16,777,216
  float* xc  = xz + 16777216;    //  8,388,608
  float* dtb = xc + 8388608;     //  8,388,608
  float* yb  = dtb + 8388608;    //  8,388,608  (ends at 41,943,040 < 131,072,000)

  embed_kernel<<<M_, 256, 0, stream>>>(tokens, embed, x);

  for (int l = 0; l < 2; ++l) {
    rmsnorm_kernel<<<M_, 256, 0, stream>>>(x, norm_w + l * D_, xn);
    // xz = xn @ W_in  (4096 x 4096 x 1024)
    gemm_f32<false><<<dim3((2 * E_) / 64, M_ / 64), 256, 0, stream>>>(
        xn, W_in + (size_t)l * D_ * 2 * E_, xz,
        M_, 2 * E_, D_, D_, 2 * E_, 2 * E_, 0, nullptr);
    // xc = silu(conv(xz[:, :E]) + b)
    conv_silu_kernel<<<(M_ * E_) / 256, 256, 0, stream>>>(
        xz, conv_w + l * E_ * 4, conv_b + l * E_, xc);
    // dbl = xc @ W_xproj  (4096 x 96 x 2048)
    gemm_f32<false><<<dim3(2, M_ / 64), 256, 0, stream>>>(
        xc, W_xproj + (size_t)l * E_ * 96, dbl,
        M_, 96, E_, E_, 96, 96, 0, nullptr);
    // dt = softplus(dbl[:, :64] @ W_dt + dt_bias)  (4096 x 2048 x 64)
    gemm_f32<false><<<dim3(E_ / 64, M_ / 64), 256, 0, stream>>>(
        dbl, W_dt + (size_t)l * RR * E_, dtb,
        M_, E_, RR, 96, E_, E_, 1, dt_bias + l * E_);
    // y = (scan(dt, B, C, xc) + xc*D) * silu(z)
    scan_kernel<<<(B_ * E_) / 16, 256, 0, stream>>>(
        dtb, dbl, xc, xz, A_log + l * E_ * NN, D_skip + l * E_, yb);
    // x += y @ W_out  (4096 x 1024 x 2048)
    gemm_f32<false><<<dim3(D_ / 64, M_ / 64), 256, 0, stream>>>(
        yb, W_out + (size_t)l * E_ * D_, x,
        M_, D_, E_, E_, D_, D_, 2, nullptr);
  }

  rmsnorm_kernel<<<M_, 256, 0, stream>>>(x, fnw, xn);
  // logits = xn @ lm_head^T  (4096 x 32000 x 1024)
  gemm_f32<true><<<dim3(32000 / 64, M_ / 64), 256, 0, stream>>>(
      xn, lm_head, out,
      M_, 32000, D_, D_, D_, 32000, 0, nullptr);
}